// Round 7
// baseline (195.035 us; speedup 1.0000x reference)
//
#include <hip/hip_runtime.h>

#define NN 50000
#define NE 800000
#define DD 128
#define BUCKETS 196   // ceil(NN/256) buckets of 256 nodes
#define PB 4096       // edges per partition block
#define PBLK 196      // ceil(NE/PB)
#define EMAX 6144     // per-bucket edge cap (mean 4096, sigma 64 -> +32 sigma)
#define BPAD 264      // ushorts per col in LDS B (256 + 8 pad)
#define PACKB 3125    // x-pack blocks: NN*DD/8/256 (8 feats per thread)
#define WTB 128       // Wt1 transpose blocks (layer 1 only)

typedef unsigned int uint_t;
typedef unsigned long long ull_t;
typedef unsigned short ush_t;
typedef __attribute__((ext_vector_type(8))) short short8;   // 8 bf16
typedef __attribute__((ext_vector_type(4))) float f32x4;    // MFMA C/D

// bf16 helpers
__device__ __forceinline__ float bflo(uint_t u) { return __uint_as_float(u << 16); }
__device__ __forceinline__ float bfhi(uint_t u) { return __uint_as_float(u & 0xffff0000u); }
__device__ __forceinline__ ush_t f2bf(float f) {  // RNE
  uint_t u = __float_as_uint(f);
  u += 0x7fffu + ((u >> 16) & 1u);
  return (ush_t)(u >> 16);
}
__device__ __forceinline__ uint_t pack2(float a, float b) {
  return (uint_t)f2bf(a) | ((uint_t)f2bf(b) << 16);
}

__device__ __forceinline__ int ld_idx(const void* ei, int is64, long long i) {
  return is64 ? (int)((const long long*)ei)[i] : ((const int*)ei)[i];
}

// Per-wave inline index-width detect (see prior rounds).
__device__ __forceinline__ int detect64(const void* ei) {
  const unsigned long long* p = (const unsigned long long*)ei;
  unsigned long long w = p[threadIdx.x & 63];
  return __ballot((w >> 32) != 0) == 0ull ? 1 : 0;
}

// Block-wide inclusive scan over 256 ints (wave shuffles + 4-wave combine).
__device__ __forceinline__ int block_incl_scan(int v, int tid, int* wsum) {
  int lane = tid & 63, wave = tid >> 6;
  int s = v;
#pragma unroll
  for (int off = 1; off < 64; off <<= 1) {
    int u = __shfl_up(s, off, 64);
    if (lane >= off) s += u;
  }
  if (lane == 63) wsum[wave] = s;
  __syncthreads();
  int base = 0;
  if (wave > 0) base += wsum[0];
  if (wave > 1) base += wsum[1];
  if (wave > 2) base += wsum[2];
  return base + s;
}

// ---------------------------------------------------------------------------
// Edge partition kernel (196 blocks only; aux work moved to csr_k's grid so
// it overlaps csr's low-parallelism CSR phase instead of serializing here).
// bcur must be zeroed before launch (hipMemsetAsync).
// ---------------------------------------------------------------------------
__global__ __launch_bounds__(256) void prep_part_k(
    const void* __restrict__ ei, int* __restrict__ bcur,
    uint_t* __restrict__ pbuf, uint_t* __restrict__ epk) {
  __shared__ int hist[256];
  __shared__ int basel[256];
  __shared__ int cur[256];
  __shared__ int gbase[256];
  __shared__ int wsum[4];
  __shared__ uint_t buf[PB];
  __shared__ unsigned char bbuf[PB];
  int tid = threadIdx.x;
  int blk = blockIdx.x;
  int is64 = detect64(ei);
  hist[tid] = 0;
  __syncthreads();
  long long base = (long long)blk * PB;
  uint_t pv[PB / 256];
#pragma unroll
  for (int i = 0; i < PB / 256; ++i) {
    long long e = base + i * 256 + tid;
    if (e < NE) {
      int s = ld_idx(ei, is64, e);
      int d = ld_idx(ei, is64, (long long)NE + e);
      pv[i] = ((uint_t)(d >> 8) << 24) | ((uint_t)(d & 255) << 16) | (uint_t)s;
      epk[e] = ((uint_t)d << 16) | (uint_t)s;
      atomicAdd(&hist[d >> 8], 1);
    } else {
      pv[i] = 0xFFFFFFFFu;
    }
  }
  __syncthreads();
  int hv = hist[tid];
  int incl = block_incl_scan(hv, tid, wsum);
  basel[tid] = incl - hv;
  cur[tid] = incl - hv;
  if (hv > 0) gbase[tid] = atomicAdd(&bcur[tid], hv);
  __syncthreads();
#pragma unroll
  for (int i = 0; i < PB / 256; ++i) {
    uint_t p = pv[i];
    if (p != 0xFFFFFFFFu) {
      int b = p >> 24;
      int r = atomicAdd(&cur[b], 1);
      buf[r] = p & 0xFFFFFFu;
      bbuf[r] = (unsigned char)b;
    }
  }
  __syncthreads();
  int total = basel[255] + hist[255];
  for (int j = tid; j < total; j += 256) {
    int b = bbuf[j];
    int slot = gbase[b] + (j - basel[b]);
    if (slot < EMAX) pbuf[(size_t)b * EMAX + slot] = buf[j];
  }
}

// ---------------------------------------------------------------------------
// CSR build + overlapped aux work. Block map:
//   [0, BUCKETS):            per-bucket CSR (low parallelism, latency-bound)
//   [BUCKETS, +2):           uv contraction: u_a = W_l2.We_a, v_a = W_r2.We_a
//   [BUCKETS+2]:             cc = b_l2.(We1+We2) + be
//   [BUCKETS+3, +PACKB):     pack x fp32->bf16 into 8-CHUNK-MAJOR xbc layout
//                            xbc[chunk][node][16], chunk = feat>>4 (8 x 1.6 MB
//                            slices -> one per XCD L2). NT stores: the lines
//                            land in the WRONG XCD's L2 7/8 of the time, so
//                            don't allocate.
//   [BUCKETS+3+PACKB, +WTB): Wt1 transpose+pack (layer 1, K=256)
// Aux blocks backfill CUs left idle by the 196 CSR blocks.
// ---------------------------------------------------------------------------
__global__ __launch_bounds__(256) void csr_k(
    const uint_t* __restrict__ pbuf, const int* __restrict__ bcur,
    int* __restrict__ offsets, ush_t* __restrict__ srclist,
    const float* __restrict__ x, ush_t* __restrict__ xbc,
    const float* __restrict__ Wl1, const float* __restrict__ Wr1,
    const float* __restrict__ Wl2, const float* __restrict__ Wr2,
    const float* __restrict__ We, const float* __restrict__ bl2,
    const float* __restrict__ be,
    ush_t* __restrict__ Wt1, float* __restrict__ uv, float* __restrict__ cc) {
  __shared__ int cnt[256];
  __shared__ int scur[256];
  __shared__ int wsum[4];
  __shared__ int sgb, scnt, stot;
  __shared__ uint_t ebuf[EMAX];
  int tid = threadIdx.x;
  int b = blockIdx.x;
  if (b >= BUCKETS) {
    int blk2 = b - BUCKETS;
    if (blk2 < 2) {
      const float* W = blk2 ? Wr2 : Wl2;
      int base = blk2 * 256;
      int wave = tid >> 6, lane = tid & 63;
      float e0 = We[lane], e1 = We[64 + lane];
      float f0 = We[128 + lane], f1 = We[192 + lane];
      for (int k = wave * 32; k < wave * 32 + 32; ++k) {
        float m0 = W[k * DD + lane];
        float m1 = W[k * DD + 64 + lane];
        float p = m0 * e0 + m1 * e1;
        float q = m0 * f0 + m1 * f1;
#pragma unroll
        for (int off = 32; off > 0; off >>= 1) {
          p += __shfl_down(p, off, 64);
          q += __shfl_down(q, off, 64);
        }
        if (lane == 0) {
          uv[base + k] = p;
          uv[base + 128 + k] = q;
        }
      }
      return;
    }
    if (blk2 == 2) {
      if (tid < 64) {
        int k = tid;
        float p = bl2[k] * (We[k] + We[128 + k]) +
                  bl2[k + 64] * (We[k + 64] + We[192 + k]);
#pragma unroll
        for (int off = 32; off > 0; off >>= 1) p += __shfl_down(p, off, 64);
        if (k == 0) cc[0] = p + be[0];
      }
      return;
    }
    blk2 -= 3;
    if (blk2 < PACKB) {  // pack x -> 8-chunk xbc (8 feats per thread), NT
      int i = blk2 * 256 + tid;  // < 800000
      int node = i >> 4;
      int g = i & 15;            // feats g*8..g*8+7
      const float4* xp = reinterpret_cast<const float4*>(x) + (size_t)i * 2;
      float4 v0 = xp[0];
      float4 v1 = xp[1];
      uint_t oa = pack2(v0.x, v0.y);
      uint_t ob = pack2(v0.z, v0.w);
      uint_t oc = pack2(v1.x, v1.y);
      uint_t od = pack2(v1.z, v1.w);
      int chunk = g >> 1;        // (g*8)>>4
      int off16 = (g & 1) * 8;
      ull_t* dst = reinterpret_cast<ull_t*>(
          xbc + ((size_t)chunk * NN + node) * 16 + off16);
      __builtin_nontemporal_store(((ull_t)ob << 32) | oa, dst);
      __builtin_nontemporal_store(((ull_t)od << 32) | oc, dst + 1);
      return;
    }
    blk2 -= PACKB;  // Wt1 transpose
    int e = blk2 * 256 + tid;  // < 32768
    int col = e >> 8;
    int k = e & 255;
    float v = (k < DD) ? Wl1[k * DD + col] : Wr1[(k - DD) * DD + col];
    Wt1[col * 256 + k] = f2bf(v);
    return;
  }
  // ---- CSR region ----
  int v = 0;
  if (tid < BUCKETS) {
    v = bcur[tid];
    if (v > EMAX) v = EMAX;
  }
  int incl = block_incl_scan(v, tid, wsum);
  if (tid == b) { sgb = incl - v; scnt = v; }
  if (tid == BUCKETS - 1) stot = incl;
  cnt[tid] = 0;
  __syncthreads();
  int gb = sgb;
  int ecnt = scnt;
  for (int j = tid; j < ecnt; j += 256) {
    uint_t e = pbuf[(size_t)b * EMAX + j];
    ebuf[j] = e;
    atomicAdd(&cnt[(e >> 16) & 255], 1);
  }
  __syncthreads();
  int c = cnt[tid];
  int incl2 = block_incl_scan(c, tid, wsum);
  int ex = incl2 - c;
  scur[tid] = ex;
  int node = b * 256 + tid;
  if (node < NN) offsets[node] = gb + ex;
  if (b == BUCKETS - 1 && tid == 0) offsets[NN] = stot;
  __syncthreads();
  for (int j = tid; j < ecnt; j += 256) {
    uint_t e = ebuf[j];
    int p = atomicAdd(&scur[(e >> 16) & 255], 1);
    srclist[gb + p] = (ush_t)(e & 0xFFFFu);
  }
}

// ---------------------------------------------------------------------------
// XCD-sliced gather-mean: 8 chunks (chunk = bid%8 == XCD id under round-robin
// dispatch; 1.6 MB slice + 1.6 MB srclist + offsets < 4 MB L2 -> resident,
// the geometry round-5 PROVED via FETCH=14.2MB) x 16-deep issue (the MLP
// round-6 proved). 4 lanes/node x 8 B (uint2) cover the 32 B chunk slice;
// per 16-edge batch all 16 gathers issue into v[16] (32 VGPR, static idx)
// before accumulation. meanb stores are NT (wrong-XCD lines, don't pollute).
// Per-feature edge accumulation order unchanged -> bit-identical results.
// ---------------------------------------------------------------------------
__global__ __launch_bounds__(256) void agg_k(const ush_t* __restrict__ xbc,
                                             const ush_t* __restrict__ srclist,
                                             const int* __restrict__ offsets,
                                             ush_t* __restrict__ meanb) {
  int bid = blockIdx.x;
  int chunk = bid & 7;
  int grp = bid >> 3;
  int tid = threadIdx.x;
  int node = grp * 64 + (tid >> 2);
  if (node >= NN) return;
  int l4 = tid & 3;
  int lane = tid & 63;
  int lb = lane & 60;  // 4-aligned group base within wave
  const ush_t* base = xbc + (size_t)chunk * NN * 16 + l4 * 4;
  int beg = offsets[node];
  int end = offsets[node + 1];
  float a0 = 0.f, a1 = 0.f, a2 = 0.f, a3 = 0.f;
  for (int c = beg; c < end; c += 16) {
    int m = end - c;
    int i0 = c + l4, i1 = c + 4 + l4, i2 = c + 8 + l4, i3 = c + 12 + l4;
    int s0 = (i0 < end) ? (int)srclist[i0] : 0;
    int s1 = (i1 < end) ? (int)srclist[i1] : 0;
    int s2 = (i2 < end) ? (int)srclist[i2] : 0;
    int s3 = (i3 < end) ? (int)srclist[i3] : 0;
    uint2 v[16];
#pragma unroll
    for (int j = 0; j < 4; ++j)
      v[j] = *reinterpret_cast<const uint2*>(base + (size_t)__shfl(s0, lb + j, 64) * 16);
#pragma unroll
    for (int j = 0; j < 4; ++j)
      v[4 + j] = *reinterpret_cast<const uint2*>(base + (size_t)__shfl(s1, lb + j, 64) * 16);
#pragma unroll
    for (int j = 0; j < 4; ++j)
      v[8 + j] = *reinterpret_cast<const uint2*>(base + (size_t)__shfl(s2, lb + j, 64) * 16);
#pragma unroll
    for (int j = 0; j < 4; ++j)
      v[12 + j] = *reinterpret_cast<const uint2*>(base + (size_t)__shfl(s3, lb + j, 64) * 16);
#pragma unroll
    for (int j = 0; j < 16; ++j) {
      if (j < m) {  // uniform across the node's 4 lanes
        a0 += bflo(v[j].x); a1 += bfhi(v[j].x);
        a2 += bflo(v[j].y); a3 += bfhi(v[j].y);
      }
    }
  }
  float inv = 1.0f / fmaxf((float)(end - beg), 1.0f);
  uint_t o0 = pack2(a0 * inv, a1 * inv);
  uint_t o1 = pack2(a2 * inv, a3 * inv);
  __builtin_nontemporal_store(
      ((ull_t)o1 << 32) | o0,
      reinterpret_cast<ull_t*>(meanb + (size_t)node * DD + chunk * 16 + l4 * 4));
}

// ---------------------------------------------------------------------------
// Layer 1 + fused layer-2 contraction epilogue (round-3 verified structure).
// A0 from meanb [node][128]; A1 frags from 8-chunk xbc; B (Wt1) in LDS.
// ---------------------------------------------------------------------------
__global__ __launch_bounds__(256, 2) void sage_l1(
    const ush_t* __restrict__ meanb, const ush_t* __restrict__ xbc,
    const ush_t* __restrict__ Wt1, const float* __restrict__ bl,
    const float* __restrict__ uv, float2* __restrict__ t12,
    float2* __restrict__ r12) {
  __shared__ ush_t sB[128 * BPAD];
  int tid = threadIdx.x;
  int lane = tid & 63;
  int wave = tid >> 6;
  int n15 = lane & 15, quad = lane >> 4;
  int nb = blockIdx.x * 64;
#pragma unroll
  for (int it = 0; it < 16; ++it) {
    int i = it * 256 + tid;
    int col = i >> 5, c = i & 31;
    *reinterpret_cast<short8*>(&sB[col * BPAD + c * 8]) =
        reinterpret_cast<const short8*>(Wt1)[i];
  }
  __syncthreads();
  int row = nb + wave * 16 + n15;
  int arow = (row < NN) ? row : (NN - 1);
  const ush_t* a0 = meanb + (size_t)arow * DD;
  f32x4 acc[8];
#pragma unroll
  for (int t = 0; t < 8; ++t) acc[t] = (f32x4){0.f, 0.f, 0.f, 0.f};
#pragma unroll
  for (int c = 0; c < 8; ++c) {
    short8 af;
    if (c < 4) {
      af = *reinterpret_cast<const short8*>(a0 + c * 32 + quad * 8);
    } else {
      int fb = (c - 4) * 32 + quad * 8;  // global feat base 0..120
      af = *reinterpret_cast<const short8*>(
          xbc + ((size_t)(fb >> 4) * NN + arow) * 16 + (fb & 15));
    }
    int kb = c * 32 + quad * 8;
#pragma unroll
    for (int t = 0; t < 8; ++t) {
      short8 bf = *reinterpret_cast<const short8*>(&sB[(t * 16 + n15) * BPAD + kb]);
      acc[t] = __builtin_amdgcn_mfma_f32_16x16x32_bf16(af, bf, acc[t], 0, 0, 0);
    }
  }
  float p1[4] = {0.f, 0.f, 0.f, 0.f};
  float p2[4] = {0.f, 0.f, 0.f, 0.f};
  float q1[4] = {0.f, 0.f, 0.f, 0.f};
  float q2[4] = {0.f, 0.f, 0.f, 0.f};
#pragma unroll
  for (int t = 0; t < 8; ++t) {
    int col = t * 16 + n15;
    float b = bl[col];
    float U1 = uv[col];
    float U2 = uv[128 + col];
    float V1 = uv[256 + col];
    float V2 = uv[384 + col];
#pragma unroll
    for (int reg = 0; reg < 4; ++reg) {
      float h = fmaxf(acc[t][reg] + b, 0.f);
      p1[reg] += h * U1;
      p2[reg] += h * U2;
      q1[reg] += h * V1;
      q2[reg] += h * V2;
    }
  }
#pragma unroll
  for (int reg = 0; reg < 4; ++reg) {
    float a1 = p1[reg], a2 = p2[reg], b1 = q1[reg], b2 = q2[reg];
    for (int off = 8; off > 0; off >>= 1) {
      a1 += __shfl_down(a1, off, 16);
      a2 += __shfl_down(a2, off, 16);
      b1 += __shfl_down(b1, off, 16);
      b2 += __shfl_down(b2, off, 16);
    }
    int r = nb + wave * 16 + quad * 4 + reg;
    if (n15 == 0 && r < NN) {
      t12[r] = make_float2(a1, a2);
      r12[r] = make_float2(b1, b2);
    }
  }
}

// ---------------------------------------------------------------------------
// Scalar second aggregation: s12[i] = mean_{j in N(i)} t12[j] + r12[i].
// ---------------------------------------------------------------------------
__global__ __launch_bounds__(256) void agg2s_k(const float2* __restrict__ t12,
                                               const ush_t* __restrict__ srclist,
                                               const int* __restrict__ offsets,
                                               const float2* __restrict__ r12,
                                               float2* __restrict__ s12) {
  int t = blockIdx.x * 256 + threadIdx.x;
  int node = t >> 4;
  int lane = t & 15;
  int beg = offsets[node];
  int end = offsets[node + 1];
  float sx = 0.f, sy = 0.f;
  for (int c = beg + lane; c < end; c += 16) {
    int s = srclist[c];
    float2 v = t12[s];
    sx += v.x;
    sy += v.y;
  }
  for (int off = 8; off > 0; off >>= 1) {
    sx += __shfl_down(sx, off, 16);
    sy += __shfl_down(sy, off, 16);
  }
  if (lane == 0) {
    float inv = 1.0f / fmaxf((float)(end - beg), 1.0f);
    float2 r = r12[node];
    s12[node] = make_float2(sx * inv + r.x, sy * inv + r.y);
  }
}

// ---------------------------------------------------------------------------
// Edge scores: y = sigmoid(s1[src] + s2[tgt] + cc), cc = b_l2.(We1+We2)+be.
// ---------------------------------------------------------------------------
__global__ __launch_bounds__(256) void edge_k(const uint_t* __restrict__ epk,
                                              const float2* __restrict__ s12,
                                              const float* __restrict__ cc,
                                              float* __restrict__ out) {
  int e = blockIdx.x * 256 + threadIdx.x;
  uint_t p = epk[e];
  float2 a = s12[p & 0xFFFFu];
  float2 b = s12[p >> 16];
  float v = a.x + b.y + cc[0];
  out[e] = 1.0f / (1.0f + __expf(-v));
}

extern "C" void kernel_launch(void* const* d_in, const int* in_sizes, int n_in,
                              void* d_out, int out_size, void* d_ws, size_t ws_size,
                              hipStream_t stream) {
  const float* x   = (const float*)d_in[0];
  const void*  ei  = d_in[1];
  const float* Wl1 = (const float*)d_in[2];
  const float* bl1 = (const float*)d_in[3];
  const float* Wr1 = (const float*)d_in[4];
  const float* Wl2 = (const float*)d_in[5];
  const float* bl2 = (const float*)d_in[6];
  const float* Wr2 = (const float*)d_in[7];
  const float* We  = (const float*)d_in[8];
  const float* be  = (const float*)d_in[9];
  float* out = (float*)d_out;

  // Workspace (every section 16B-aligned):
  // bcur[256] | offsets[50004] | epk[NE] | pbuf[BUCKETS*EMAX] |
  // srclist[NE ush] | xbc[NN*DD ush 8-chunk-major] | meanb[NN*DD ush] |
  // t12[NN f2] | r12[NN f2] | s12[NN f2] | Wt1[32768 ush] | uv[512 f] | cc[4 f]
  int* bcur       = (int*)d_ws;
  int* offsets    = bcur + 256;
  uint_t* epk     = (uint_t*)(offsets + 50004);
  uint_t* pbuf    = epk + NE;
  ush_t* srclist  = (ush_t*)(pbuf + (size_t)BUCKETS * EMAX);
  ush_t* xbc      = srclist + NE;
  ush_t* meanb    = xbc + (size_t)NN * DD;
  float2* t12     = (float2*)(meanb + (size_t)NN * DD);
  float2* r12     = t12 + NN;
  float2* s12     = r12 + NN;
  ush_t* Wt1      = (ush_t*)(s12 + NN);
  float* uv       = (float*)(Wt1 + 32768);
  float* cc       = uv + 512;

  hipMemsetAsync(bcur, 0, 256 * sizeof(int), stream);
  prep_part_k<<<PBLK, 256, 0, stream>>>(ei, bcur, pbuf, epk);

  csr_k<<<BUCKETS + 3 + PACKB + WTB, 256, 0, stream>>>(
      pbuf, bcur, offsets, srclist, x, xbc, Wl1, Wr1, Wl2, Wr2, We, bl2, be,
      Wt1, uv, cc);

  // 782 node-groups (64 nodes) x 8 XCD-pinned feature chunks
  agg_k<<<((NN + 63) / 64) * 8, 256, 0, stream>>>(xbc, srclist, offsets, meanb);

  sage_l1<<<(NN + 63) / 64, 256, 0, stream>>>(meanb, xbc, Wt1, bl1, uv, t12, r12);

  agg2s_k<<<(NN * 16) / 256, 256, 0, stream>>>(t12, srclist, offsets, r12, s12);

  edge_k<<<NE / 256, 256, 0, stream>>>(epk, s12, cc, out);
}

// Round 8
// 194.769 us; speedup vs baseline: 1.0014x; 1.0014x over previous
//
#include <hip/hip_runtime.h>

#define NN 50000
#define NE 800000
#define DD 128
#define BUCKETS 196   // ceil(NN/256) buckets of 256 nodes
#define PB 4096       // edges per partition block
#define PBLK 196      // ceil(NE/PB)
#define EMAX 6144     // per-bucket edge cap (mean 4096, sigma 64 -> +32 sigma)
#define BPAD 264      // ushorts per col in LDS B (256 + 8 pad)
#define PACKB 3125    // x-pack blocks: NN*DD/8/256 (8 feats per thread)
#define WTB 128       // Wt1 transpose blocks (layer 1 only)

typedef unsigned int uint_t;
typedef unsigned long long ull_t;
typedef unsigned short ush_t;
typedef __attribute__((ext_vector_type(8))) short short8;   // 8 bf16
typedef __attribute__((ext_vector_type(4))) float f32x4;    // MFMA C/D

// bf16 helpers
__device__ __forceinline__ float bflo(uint_t u) { return __uint_as_float(u << 16); }
__device__ __forceinline__ float bfhi(uint_t u) { return __uint_as_float(u & 0xffff0000u); }
__device__ __forceinline__ ush_t f2bf(float f) {  // RNE
  uint_t u = __float_as_uint(f);
  u += 0x7fffu + ((u >> 16) & 1u);
  return (ush_t)(u >> 16);
}
__device__ __forceinline__ uint_t pack2(float a, float b) {
  return (uint_t)f2bf(a) | ((uint_t)f2bf(b) << 16);
}

__device__ __forceinline__ int ld_idx(const void* ei, int is64, long long i) {
  return is64 ? (int)((const long long*)ei)[i] : ((const int*)ei)[i];
}

// Per-wave inline index-width detect (see prior rounds).
__device__ __forceinline__ int detect64(const void* ei) {
  const unsigned long long* p = (const unsigned long long*)ei;
  unsigned long long w = p[threadIdx.x & 63];
  return __ballot((w >> 32) != 0) == 0ull ? 1 : 0;
}

// Block-wide inclusive scan over 256 ints (wave shuffles + 4-wave combine).
__device__ __forceinline__ int block_incl_scan(int v, int tid, int* wsum) {
  int lane = tid & 63, wave = tid >> 6;
  int s = v;
#pragma unroll
  for (int off = 1; off < 64; off <<= 1) {
    int u = __shfl_up(s, off, 64);
    if (lane >= off) s += u;
  }
  if (lane == 63) wsum[wave] = s;
  __syncthreads();
  int base = 0;
  if (wave > 0) base += wsum[0];
  if (wave > 1) base += wsum[1];
  if (wave > 2) base += wsum[2];
  return base + s;
}

// ---------------------------------------------------------------------------
// Edge partition kernel (196 blocks; aux work lives in csr_k's grid).
// bcur must be zeroed before launch (hipMemsetAsync).
// ---------------------------------------------------------------------------
__global__ __launch_bounds__(256) void prep_part_k(
    const void* __restrict__ ei, int* __restrict__ bcur,
    uint_t* __restrict__ pbuf, uint_t* __restrict__ epk) {
  __shared__ int hist[256];
  __shared__ int basel[256];
  __shared__ int cur[256];
  __shared__ int gbase[256];
  __shared__ int wsum[4];
  __shared__ uint_t buf[PB];
  __shared__ unsigned char bbuf[PB];
  int tid = threadIdx.x;
  int blk = blockIdx.x;
  int is64 = detect64(ei);
  hist[tid] = 0;
  __syncthreads();
  long long base = (long long)blk * PB;
  uint_t pv[PB / 256];
#pragma unroll
  for (int i = 0; i < PB / 256; ++i) {
    long long e = base + i * 256 + tid;
    if (e < NE) {
      int s = ld_idx(ei, is64, e);
      int d = ld_idx(ei, is64, (long long)NE + e);
      pv[i] = ((uint_t)(d >> 8) << 24) | ((uint_t)(d & 255) << 16) | (uint_t)s;
      epk[e] = ((uint_t)d << 16) | (uint_t)s;
      atomicAdd(&hist[d >> 8], 1);
    } else {
      pv[i] = 0xFFFFFFFFu;
    }
  }
  __syncthreads();
  int hv = hist[tid];
  int incl = block_incl_scan(hv, tid, wsum);
  basel[tid] = incl - hv;
  cur[tid] = incl - hv;
  if (hv > 0) gbase[tid] = atomicAdd(&bcur[tid], hv);
  __syncthreads();
#pragma unroll
  for (int i = 0; i < PB / 256; ++i) {
    uint_t p = pv[i];
    if (p != 0xFFFFFFFFu) {
      int b = p >> 24;
      int r = atomicAdd(&cur[b], 1);
      buf[r] = p & 0xFFFFFFu;
      bbuf[r] = (unsigned char)b;
    }
  }
  __syncthreads();
  int total = basel[255] + hist[255];
  for (int j = tid; j < total; j += 256) {
    int b = bbuf[j];
    int slot = gbase[b] + (j - basel[b]);
    if (slot < EMAX) pbuf[(size_t)b * EMAX + slot] = buf[j];
  }
}

// ---------------------------------------------------------------------------
// CSR build + overlapped aux work. Block map:
//   [0, BUCKETS):            per-bucket CSR (low parallelism, latency-bound)
//   [BUCKETS, +2):           uv contraction: u_a = W_l2.We_a, v_a = W_r2.We_a
//   [BUCKETS+2]:             cc = b_l2.(We1+We2) + be
//   [BUCKETS+3, +PACKB):     pack x fp32->bf16 into 4-CHUNK-MAJOR xbc:
//                            xbc[chunk][node][32], chunk = feat>>5 (4 x 3.2 MB
//                            slices). NT stores (lines land in the wrong
//                            XCD's L2 most of the time -> don't allocate).
//   [BUCKETS+3+PACKB, +WTB): Wt1 transpose+pack (layer 1, K=256)
// ---------------------------------------------------------------------------
__global__ __launch_bounds__(256) void csr_k(
    const uint_t* __restrict__ pbuf, const int* __restrict__ bcur,
    int* __restrict__ offsets, ush_t* __restrict__ srclist,
    const float* __restrict__ x, ush_t* __restrict__ xbc,
    const float* __restrict__ Wl1, const float* __restrict__ Wr1,
    const float* __restrict__ Wl2, const float* __restrict__ Wr2,
    const float* __restrict__ We, const float* __restrict__ bl2,
    const float* __restrict__ be,
    ush_t* __restrict__ Wt1, float* __restrict__ uv, float* __restrict__ cc) {
  __shared__ int cnt[256];
  __shared__ int scur[256];
  __shared__ int wsum[4];
  __shared__ int sgb, scnt, stot;
  __shared__ uint_t ebuf[EMAX];
  int tid = threadIdx.x;
  int b = blockIdx.x;
  if (b >= BUCKETS) {
    int blk2 = b - BUCKETS;
    if (blk2 < 2) {
      const float* W = blk2 ? Wr2 : Wl2;
      int base = blk2 * 256;
      int wave = tid >> 6, lane = tid & 63;
      float e0 = We[lane], e1 = We[64 + lane];
      float f0 = We[128 + lane], f1 = We[192 + lane];
      for (int k = wave * 32; k < wave * 32 + 32; ++k) {
        float m0 = W[k * DD + lane];
        float m1 = W[k * DD + 64 + lane];
        float p = m0 * e0 + m1 * e1;
        float q = m0 * f0 + m1 * f1;
#pragma unroll
        for (int off = 32; off > 0; off >>= 1) {
          p += __shfl_down(p, off, 64);
          q += __shfl_down(q, off, 64);
        }
        if (lane == 0) {
          uv[base + k] = p;
          uv[base + 128 + k] = q;
        }
      }
      return;
    }
    if (blk2 == 2) {
      if (tid < 64) {
        int k = tid;
        float p = bl2[k] * (We[k] + We[128 + k]) +
                  bl2[k + 64] * (We[k + 64] + We[192 + k]);
#pragma unroll
        for (int off = 32; off > 0; off >>= 1) p += __shfl_down(p, off, 64);
        if (k == 0) cc[0] = p + be[0];
      }
      return;
    }
    blk2 -= 3;
    if (blk2 < PACKB) {  // pack x -> 4-chunk xbc (8 feats per thread), NT
      int i = blk2 * 256 + tid;  // < 800000
      int node = i >> 4;
      int g = i & 15;            // feats g*8..g*8+7
      const float4* xp = reinterpret_cast<const float4*>(x) + (size_t)i * 2;
      float4 v0 = xp[0];
      float4 v1 = xp[1];
      uint_t oa = pack2(v0.x, v0.y);
      uint_t ob = pack2(v0.z, v0.w);
      uint_t oc = pack2(v1.x, v1.y);
      uint_t od = pack2(v1.z, v1.w);
      int chunk = g >> 2;        // (g*8)>>5
      int off32 = (g & 3) * 8;   // offset within 32-feat chunk
      ull_t* dst = reinterpret_cast<ull_t*>(
          xbc + ((size_t)chunk * NN + node) * 32 + off32);
      __builtin_nontemporal_store(((ull_t)ob << 32) | oa, dst);
      __builtin_nontemporal_store(((ull_t)od << 32) | oc, dst + 1);
      return;
    }
    blk2 -= PACKB;  // Wt1 transpose
    int e = blk2 * 256 + tid;  // < 32768
    int col = e >> 8;
    int k = e & 255;
    float v = (k < DD) ? Wl1[k * DD + col] : Wr1[(k - DD) * DD + col];
    Wt1[col * 256 + k] = f2bf(v);
    return;
  }
  // ---- CSR region ----
  int v = 0;
  if (tid < BUCKETS) {
    v = bcur[tid];
    if (v > EMAX) v = EMAX;
  }
  int incl = block_incl_scan(v, tid, wsum);
  if (tid == b) { sgb = incl - v; scnt = v; }
  if (tid == BUCKETS - 1) stot = incl;
  cnt[tid] = 0;
  __syncthreads();
  int gb = sgb;
  int ecnt = scnt;
  for (int j = tid; j < ecnt; j += 256) {
    uint_t e = pbuf[(size_t)b * EMAX + j];
    ebuf[j] = e;
    atomicAdd(&cnt[(e >> 16) & 255], 1);
  }
  __syncthreads();
  int c = cnt[tid];
  int incl2 = block_incl_scan(c, tid, wsum);
  int ex = incl2 - c;
  scur[tid] = ex;
  int node = b * 256 + tid;
  if (node < NN) offsets[node] = gb + ex;
  if (b == BUCKETS - 1 && tid == 0) offsets[NN] = stot;
  __syncthreads();
  for (int j = tid; j < ecnt; j += 256) {
    uint_t e = ebuf[j];
    int p = atomicAdd(&scur[(e >> 16) & 255], 1);
    srclist[gb + p] = (ush_t)(e & 0xFFFFu);
  }
}

// ---------------------------------------------------------------------------
// XCD-sliced gather-mean v3: 4 chunks x 64B requests (round-6 geometry, the
// best measured) with per-gather overhead stripped:
//  - DPP quad_perm broadcast (1 VALU, no LDS pipe) replaces __shfl/ds_bpermute
//  - uniform SGPR chunk base + 32-bit voffset (no 64-bit addr chain)
//  - 8-deep uint4 issue (32 VGPR in flight); tail clamps to end-1 (warm line)
//  - srclist via NT loads (streamed) -> per-XCD L2 footprint ~3.3 MB < 4 MB
// Per-feature edge accumulation order unchanged -> bit-identical results.
// ---------------------------------------------------------------------------
#define ACC8(v)                                                  \
  a0 += bflo((v).x); a1 += bfhi((v).x); a2 += bflo((v).y);       \
  a3 += bfhi((v).y); a4 += bflo((v).z); a5 += bfhi((v).z);       \
  a6 += bflo((v).w); a7 += bfhi((v).w);

__global__ __launch_bounds__(256) void agg_k(const ush_t* __restrict__ xbc,
                                             const ush_t* __restrict__ srclist,
                                             const int* __restrict__ offsets,
                                             ush_t* __restrict__ meanb) {
  int bid = blockIdx.x;
  int chunk = bid & 3;
  int grp = bid >> 2;
  int tid = threadIdx.x;
  int node = grp * 64 + (tid >> 2);
  if (node >= NN) return;
  int l4 = tid & 3;
  const ush_t* cb = xbc + (size_t)chunk * NN * 32;  // wave-uniform chunk base
  int loff = l4 * 8;                                 // lane offset (elements)
  int beg = offsets[node];
  int end = offsets[node + 1];
  float a0 = 0.f, a1 = 0.f, a2 = 0.f, a3 = 0.f;
  float a4 = 0.f, a5 = 0.f, a6 = 0.f, a7 = 0.f;
  for (int c = beg; c < end; c += 8) {
    int last = end - 1;
    int ia = c + l4;      ia = ia < last ? ia : last;
    int ib = c + 4 + l4;  ib = ib < last ? ib : last;
    int sa = (int)__builtin_nontemporal_load(srclist + ia);
    int sb = (int)__builtin_nontemporal_load(srclist + ib);
    // quad_perm broadcast: all 4 lanes of the node's quad get edge j's src
    int t0 = __builtin_amdgcn_mov_dpp(sa, 0x00, 0xf, 0xf, false);
    int t1 = __builtin_amdgcn_mov_dpp(sa, 0x55, 0xf, 0xf, false);
    int t2 = __builtin_amdgcn_mov_dpp(sa, 0xAA, 0xf, 0xf, false);
    int t3 = __builtin_amdgcn_mov_dpp(sa, 0xFF, 0xf, 0xf, false);
    int t4 = __builtin_amdgcn_mov_dpp(sb, 0x00, 0xf, 0xf, false);
    int t5 = __builtin_amdgcn_mov_dpp(sb, 0x55, 0xf, 0xf, false);
    int t6 = __builtin_amdgcn_mov_dpp(sb, 0xAA, 0xf, 0xf, false);
    int t7 = __builtin_amdgcn_mov_dpp(sb, 0xFF, 0xf, 0xf, false);
    uint4 v0 = *reinterpret_cast<const uint4*>(cb + ((t0 << 5) + loff));
    uint4 v1 = *reinterpret_cast<const uint4*>(cb + ((t1 << 5) + loff));
    uint4 v2 = *reinterpret_cast<const uint4*>(cb + ((t2 << 5) + loff));
    uint4 v3 = *reinterpret_cast<const uint4*>(cb + ((t3 << 5) + loff));
    uint4 v4 = *reinterpret_cast<const uint4*>(cb + ((t4 << 5) + loff));
    uint4 v5 = *reinterpret_cast<const uint4*>(cb + ((t5 << 5) + loff));
    uint4 v6 = *reinterpret_cast<const uint4*>(cb + ((t6 << 5) + loff));
    uint4 v7 = *reinterpret_cast<const uint4*>(cb + ((t7 << 5) + loff));
    int m = end - c;  // uniform within the quad
    ACC8(v0);
    if (m > 1) { ACC8(v1); }
    if (m > 2) { ACC8(v2); }
    if (m > 3) { ACC8(v3); }
    if (m > 4) { ACC8(v4); }
    if (m > 5) { ACC8(v5); }
    if (m > 6) { ACC8(v6); }
    if (m > 7) { ACC8(v7); }
  }
  float inv = 1.0f / fmaxf((float)(end - beg), 1.0f);
  uint_t o0 = pack2(a0 * inv, a1 * inv);
  uint_t o1 = pack2(a2 * inv, a3 * inv);
  uint_t o2 = pack2(a4 * inv, a5 * inv);
  uint_t o3 = pack2(a6 * inv, a7 * inv);
  ull_t* dst = reinterpret_cast<ull_t*>(meanb + (size_t)node * DD + chunk * 32 + loff);
  __builtin_nontemporal_store(((ull_t)o1 << 32) | o0, dst);
  __builtin_nontemporal_store(((ull_t)o3 << 32) | o2, dst + 1);
}

// ---------------------------------------------------------------------------
// Layer 1 + fused layer-2 contraction epilogue (round-3 verified structure).
// A0 from meanb [node][128]; A1 frags from 4-chunk xbc (16 rows x 64 B = 1 KB
// contiguous per wave-load); B (Wt1) in LDS.
// ---------------------------------------------------------------------------
__global__ __launch_bounds__(256, 2) void sage_l1(
    const ush_t* __restrict__ meanb, const ush_t* __restrict__ xbc,
    const ush_t* __restrict__ Wt1, const float* __restrict__ bl,
    const float* __restrict__ uv, float2* __restrict__ t12,
    float2* __restrict__ r12) {
  __shared__ ush_t sB[128 * BPAD];
  int tid = threadIdx.x;
  int lane = tid & 63;
  int wave = tid >> 6;
  int n15 = lane & 15, quad = lane >> 4;
  int nb = blockIdx.x * 64;
#pragma unroll
  for (int it = 0; it < 16; ++it) {
    int i = it * 256 + tid;
    int col = i >> 5, c = i & 31;
    *reinterpret_cast<short8*>(&sB[col * BPAD + c * 8]) =
        reinterpret_cast<const short8*>(Wt1)[i];
  }
  __syncthreads();
  int row = nb + wave * 16 + n15;
  int arow = (row < NN) ? row : (NN - 1);
  const ush_t* a0 = meanb + (size_t)arow * DD;
  f32x4 acc[8];
#pragma unroll
  for (int t = 0; t < 8; ++t) acc[t] = (f32x4){0.f, 0.f, 0.f, 0.f};
#pragma unroll
  for (int c = 0; c < 8; ++c) {
    short8 af;
    if (c < 4) {
      af = *reinterpret_cast<const short8*>(a0 + c * 32 + quad * 8);
    } else {
      af = *reinterpret_cast<const short8*>(
          xbc + ((size_t)(c - 4) * NN + arow) * 32 + quad * 8);
    }
    int kb = c * 32 + quad * 8;
#pragma unroll
    for (int t = 0; t < 8; ++t) {
      short8 bf = *reinterpret_cast<const short8*>(&sB[(t * 16 + n15) * BPAD + kb]);
      acc[t] = __builtin_amdgcn_mfma_f32_16x16x32_bf16(af, bf, acc[t], 0, 0, 0);
    }
  }
  float p1[4] = {0.f, 0.f, 0.f, 0.f};
  float p2[4] = {0.f, 0.f, 0.f, 0.f};
  float q1[4] = {0.f, 0.f, 0.f, 0.f};
  float q2[4] = {0.f, 0.f, 0.f, 0.f};
#pragma unroll
  for (int t = 0; t < 8; ++t) {
    int col = t * 16 + n15;
    float b = bl[col];
    float U1 = uv[col];
    float U2 = uv[128 + col];
    float V1 = uv[256 + col];
    float V2 = uv[384 + col];
#pragma unroll
    for (int reg = 0; reg < 4; ++reg) {
      float h = fmaxf(acc[t][reg] + b, 0.f);
      p1[reg] += h * U1;
      p2[reg] += h * U2;
      q1[reg] += h * V1;
      q2[reg] += h * V2;
    }
  }
#pragma unroll
  for (int reg = 0; reg < 4; ++reg) {
    float a1 = p1[reg], a2 = p2[reg], b1 = q1[reg], b2 = q2[reg];
    for (int off = 8; off > 0; off >>= 1) {
      a1 += __shfl_down(a1, off, 16);
      a2 += __shfl_down(a2, off, 16);
      b1 += __shfl_down(b1, off, 16);
      b2 += __shfl_down(b2, off, 16);
    }
    int r = nb + wave * 16 + quad * 4 + reg;
    if (n15 == 0 && r < NN) {
      t12[r] = make_float2(a1, a2);
      r12[r] = make_float2(b1, b2);
    }
  }
}

// ---------------------------------------------------------------------------
// Scalar second aggregation: s12[i] = mean_{j in N(i)} t12[j] + r12[i].
// ---------------------------------------------------------------------------
__global__ __launch_bounds__(256) void agg2s_k(const float2* __restrict__ t12,
                                               const ush_t* __restrict__ srclist,
                                               const int* __restrict__ offsets,
                                               const float2* __restrict__ r12,
                                               float2* __restrict__ s12) {
  int t = blockIdx.x * 256 + threadIdx.x;
  int node = t >> 4;
  int lane = t & 15;
  int beg = offsets[node];
  int end = offsets[node + 1];
  float sx = 0.f, sy = 0.f;
  for (int c = beg + lane; c < end; c += 16) {
    int s = srclist[c];
    float2 v = t12[s];
    sx += v.x;
    sy += v.y;
  }
  for (int off = 8; off > 0; off >>= 1) {
    sx += __shfl_down(sx, off, 16);
    sy += __shfl_down(sy, off, 16);
  }
  if (lane == 0) {
    float inv = 1.0f / fmaxf((float)(end - beg), 1.0f);
    float2 r = r12[node];
    s12[node] = make_float2(sx * inv + r.x, sy * inv + r.y);
  }
}

// ---------------------------------------------------------------------------
// Edge scores: y = sigmoid(s1[src] + s2[tgt] + cc), cc = b_l2.(We1+We2)+be.
// ---------------------------------------------------------------------------
__global__ __launch_bounds__(256) void edge_k(const uint_t* __restrict__ epk,
                                              const float2* __restrict__ s12,
                                              const float* __restrict__ cc,
                                              float* __restrict__ out) {
  int e = blockIdx.x * 256 + threadIdx.x;
  uint_t p = epk[e];
  float2 a = s12[p & 0xFFFFu];
  float2 b = s12[p >> 16];
  float v = a.x + b.y + cc[0];
  out[e] = 1.0f / (1.0f + __expf(-v));
}

extern "C" void kernel_launch(void* const* d_in, const int* in_sizes, int n_in,
                              void* d_out, int out_size, void* d_ws, size_t ws_size,
                              hipStream_t stream) {
  const float* x   = (const float*)d_in[0];
  const void*  ei  = d_in[1];
  const float* Wl1 = (const float*)d_in[2];
  const float* bl1 = (const float*)d_in[3];
  const float* Wr1 = (const float*)d_in[4];
  const float* Wl2 = (const float*)d_in[5];
  const float* bl2 = (const float*)d_in[6];
  const float* Wr2 = (const float*)d_in[7];
  const float* We  = (const float*)d_in[8];
  const float* be  = (const float*)d_in[9];
  float* out = (float*)d_out;

  // Workspace (every section 16B-aligned):
  // bcur[256] | offsets[50004] | epk[NE] | pbuf[BUCKETS*EMAX] |
  // srclist[NE ush] | xbc[NN*DD ush 4-chunk-major] | meanb[NN*DD ush] |
  // t12[NN f2] | r12[NN f2] | s12[NN f2] | Wt1[32768 ush] | uv[512 f] | cc[4 f]
  int* bcur       = (int*)d_ws;
  int* offsets    = bcur + 256;
  uint_t* epk     = (uint_t*)(offsets + 50004);
  uint_t* pbuf    = epk + NE;
  ush_t* srclist  = (ush_t*)(pbuf + (size_t)BUCKETS * EMAX);
  ush_t* xbc      = srclist + NE;
  ush_t* meanb    = xbc + (size_t)NN * DD;
  float2* t12     = (float2*)(meanb + (size_t)NN * DD);
  float2* r12     = t12 + NN;
  float2* s12     = r12 + NN;
  ush_t* Wt1      = (ush_t*)(s12 + NN);
  float* uv       = (float*)(Wt1 + 32768);
  float* cc       = uv + 512;

  hipMemsetAsync(bcur, 0, 256 * sizeof(int), stream);
  prep_part_k<<<PBLK, 256, 0, stream>>>(ei, bcur, pbuf, epk);

  csr_k<<<BUCKETS + 3 + PACKB + WTB, 256, 0, stream>>>(
      pbuf, bcur, offsets, srclist, x, xbc, Wl1, Wr1, Wl2, Wr2, We, bl2, be,
      Wt1, uv, cc);

  // 782 node-groups (64 nodes) x 4 XCD-pinned feature chunks
  agg_k<<<((NN + 63) / 64) * 4, 256, 0, stream>>>(xbc, srclist, offsets, meanb);

  sage_l1<<<(NN + 63) / 64, 256, 0, stream>>>(meanb, xbc, Wt1, bl1, uv, t12, r12);

  agg2s_k<<<(NN * 16) / 256, 256, 0, stream>>>(t12, srclist, offsets, r12, s12);

  edge_k<<<NE / 256, 256, 0, stream>>>(epk, s12, cc, out);
}

// Round 10
// 176.220 us; speedup vs baseline: 1.1068x; 1.1053x over previous
//
#include <hip/hip_runtime.h>

#define NN 50000
#define NE 800000
#define DD 128
#define BUCKETS 196   // ceil(NN/256) buckets of 256 nodes
#define PB 4096       // edges per partition block
#define PBLK 196      // ceil(NE/PB)
#define EMAX 6144     // per-bucket edge cap (mean 4096, sigma 64 -> +32 sigma)
#define BPAD 264      // ushorts per col in LDS B (256 + 8 pad)
#define PACKB 3125    // x-pack blocks: NN*DD/8/256 (8 feats per thread)
#define WTB 128       // Wt1 transpose blocks (layer 1 only)

typedef unsigned int uint_t;
typedef unsigned long long ull_t;
typedef unsigned short ush_t;
typedef __attribute__((ext_vector_type(8))) short short8;   // 8 bf16
typedef __attribute__((ext_vector_type(4))) float f32x4;    // MFMA C/D

// bf16 helpers
__device__ __forceinline__ float bflo(uint_t u) { return __uint_as_float(u << 16); }
__device__ __forceinline__ float bfhi(uint_t u) { return __uint_as_float(u & 0xffff0000u); }
__device__ __forceinline__ ush_t f2bf(float f) {  // RNE
  uint_t u = __float_as_uint(f);
  u += 0x7fffu + ((u >> 16) & 1u);
  return (ush_t)(u >> 16);
}
__device__ __forceinline__ uint_t pack2(float a, float b) {
  return (uint_t)f2bf(a) | ((uint_t)f2bf(b) << 16);
}

__device__ __forceinline__ int ld_idx(const void* ei, int is64, long long i) {
  return is64 ? (int)((const long long*)ei)[i] : ((const int*)ei)[i];
}

// Per-wave inline index-width detect (see prior rounds).
__device__ __forceinline__ int detect64(const void* ei) {
  const unsigned long long* p = (const unsigned long long*)ei;
  unsigned long long w = p[threadIdx.x & 63];
  return __ballot((w >> 32) != 0) == 0ull ? 1 : 0;
}

// Block-wide inclusive scan over 256 ints (wave shuffles + 4-wave combine).
__device__ __forceinline__ int block_incl_scan(int v, int tid, int* wsum) {
  int lane = tid & 63, wave = tid >> 6;
  int s = v;
#pragma unroll
  for (int off = 1; off < 64; off <<= 1) {
    int u = __shfl_up(s, off, 64);
    if (lane >= off) s += u;
  }
  if (lane == 63) wsum[wave] = s;
  __syncthreads();
  int base = 0;
  if (wave > 0) base += wsum[0];
  if (wave > 1) base += wsum[1];
  if (wave > 2) base += wsum[2];
  return base + s;
}

// ---------------------------------------------------------------------------
// Fused prep+partition kernel. Block map (in dispatch order):
//   [0, PBLK):               edge partition + epk emit
//   [PBLK, PBLK+2):          uv contraction: u_a = W_l2 . We_a, v_a = W_r2 . We_a
//   [PBLK+2]:                cc = b_l2 . (We1+We2) + be
//   [PBLK+3, +PACKB):        pack x fp32->bf16 into 4-CHUNK-MAJOR xbc layout:
//                            xbc[chunk][node][32], chunk = feat>>5 (4 chunks,
//                            3.2 MB each -> fits one XCD's 4 MB L2)
//   [PBLK+3+PACKB, +WTB):    Wt1 transpose+pack (layer 1 only, K=256)
// bcur must be zeroed before launch (hipMemsetAsync).
// ---------------------------------------------------------------------------
__global__ __launch_bounds__(256) void prep_part_k(
    const void* __restrict__ ei, int* __restrict__ bcur,
    uint_t* __restrict__ pbuf, uint_t* __restrict__ epk,
    const float* __restrict__ x, ush_t* __restrict__ xbc,
    const float* __restrict__ Wl1, const float* __restrict__ Wr1,
    const float* __restrict__ Wl2, const float* __restrict__ Wr2,
    const float* __restrict__ We, const float* __restrict__ bl2,
    const float* __restrict__ be,
    ush_t* __restrict__ Wt1, float* __restrict__ uv, float* __restrict__ cc) {
  __shared__ int hist[256];
  __shared__ int basel[256];
  __shared__ int cur[256];
  __shared__ int gbase[256];
  __shared__ int wsum[4];
  __shared__ uint_t buf[PB];
  __shared__ unsigned char bbuf[PB];
  int tid = threadIdx.x;
  int blk = blockIdx.x;
  if (blk >= PBLK) {
    int blk2 = blk - PBLK;
    if (blk2 < 2) {
      const float* W = blk2 ? Wr2 : Wl2;
      int base = blk2 * 256;
      int wave = tid >> 6, lane = tid & 63;
      float e0 = We[lane], e1 = We[64 + lane];
      float f0 = We[128 + lane], f1 = We[192 + lane];
      for (int k = wave * 32; k < wave * 32 + 32; ++k) {
        float m0 = W[k * DD + lane];
        float m1 = W[k * DD + 64 + lane];
        float p = m0 * e0 + m1 * e1;
        float q = m0 * f0 + m1 * f1;
#pragma unroll
        for (int off = 32; off > 0; off >>= 1) {
          p += __shfl_down(p, off, 64);
          q += __shfl_down(q, off, 64);
        }
        if (lane == 0) {
          uv[base + k] = p;
          uv[base + 128 + k] = q;
        }
      }
      return;
    }
    if (blk2 == 2) {
      if (tid < 64) {
        int k = tid;
        float p = bl2[k] * (We[k] + We[128 + k]) +
                  bl2[k + 64] * (We[k + 64] + We[192 + k]);
#pragma unroll
        for (int off = 32; off > 0; off >>= 1) p += __shfl_down(p, off, 64);
        if (k == 0) cc[0] = p + be[0];
      }
      return;
    }
    blk2 -= 3;
    if (blk2 < PACKB) {  // pack x -> 4-chunk xbc (8 feats per thread)
      int i = blk2 * 256 + tid;  // < 800000
      int node = i >> 4;
      int g = i & 15;            // 8-feat group: feats g*8..g*8+7
      const float4* xp = reinterpret_cast<const float4*>(x) + (size_t)i * 2;
      float4 v0 = xp[0];
      float4 v1 = xp[1];
      uint4 o;
      o.x = pack2(v0.x, v0.y);
      o.y = pack2(v0.z, v0.w);
      o.z = pack2(v1.x, v1.y);
      o.w = pack2(v1.z, v1.w);
      int chunk = g >> 2;        // (g*8)>>5
      int off32 = (g & 3) * 8;   // offset within 32-feat chunk
      *reinterpret_cast<uint4*>(xbc + ((size_t)chunk * NN + node) * 32 + off32) = o;
      return;
    }
    blk2 -= PACKB;  // Wt1 transpose
    int e = blk2 * 256 + tid;  // < 32768
    int col = e >> 8;
    int k = e & 255;
    float v = (k < DD) ? Wl1[k * DD + col] : Wr1[(k - DD) * DD + col];
    Wt1[col * 256 + k] = f2bf(v);
    return;
  }
  // ---- partition region ----
  int is64 = detect64(ei);
  hist[tid] = 0;
  __syncthreads();
  long long base = (long long)blk * PB;
  uint_t pv[PB / 256];
#pragma unroll
  for (int i = 0; i < PB / 256; ++i) {
    long long e = base + i * 256 + tid;
    if (e < NE) {
      int s = ld_idx(ei, is64, e);
      int d = ld_idx(ei, is64, (long long)NE + e);
      pv[i] = ((uint_t)(d >> 8) << 24) | ((uint_t)(d & 255) << 16) | (uint_t)s;
      epk[e] = ((uint_t)d << 16) | (uint_t)s;
      atomicAdd(&hist[d >> 8], 1);
    } else {
      pv[i] = 0xFFFFFFFFu;
    }
  }
  __syncthreads();
  int hv = hist[tid];
  int incl = block_incl_scan(hv, tid, wsum);
  basel[tid] = incl - hv;
  cur[tid] = incl - hv;
  if (hv > 0) gbase[tid] = atomicAdd(&bcur[tid], hv);
  __syncthreads();
#pragma unroll
  for (int i = 0; i < PB / 256; ++i) {
    uint_t p = pv[i];
    if (p != 0xFFFFFFFFu) {
      int b = p >> 24;
      int r = atomicAdd(&cur[b], 1);
      buf[r] = p & 0xFFFFFFu;
      bbuf[r] = (unsigned char)b;
    }
  }
  __syncthreads();
  int total = basel[255] + hist[255];
  for (int j = tid; j < total; j += 256) {
    int b = bbuf[j];
    int slot = gbase[b] + (j - basel[b]);
    if (slot < EMAX) pbuf[(size_t)b * EMAX + slot] = buf[j];
  }
}

// ---------------------------------------------------------------------------
// Per-bucket CSR build. srclist is ushort (src < 65536) -> 1.6 MB total.
// ---------------------------------------------------------------------------
__global__ __launch_bounds__(256) void csr_k(const uint_t* __restrict__ pbuf,
                                             const int* __restrict__ bcur,
                                             int* __restrict__ offsets,
                                             ush_t* __restrict__ srclist) {
  __shared__ int cnt[256];
  __shared__ int scur[256];
  __shared__ int wsum[4];
  __shared__ int sgb, scnt, stot;
  __shared__ uint_t ebuf[EMAX];
  int tid = threadIdx.x;
  int b = blockIdx.x;
  int v = 0;
  if (tid < BUCKETS) {
    v = bcur[tid];
    if (v > EMAX) v = EMAX;
  }
  int incl = block_incl_scan(v, tid, wsum);
  if (tid == b) { sgb = incl - v; scnt = v; }
  if (tid == BUCKETS - 1) stot = incl;
  cnt[tid] = 0;
  __syncthreads();
  int gb = sgb;
  int ecnt = scnt;
  for (int j = tid; j < ecnt; j += 256) {
    uint_t e = pbuf[(size_t)b * EMAX + j];
    ebuf[j] = e;
    atomicAdd(&cnt[(e >> 16) & 255], 1);
  }
  __syncthreads();
  int c = cnt[tid];
  int incl2 = block_incl_scan(c, tid, wsum);
  int ex = incl2 - c;
  scur[tid] = ex;
  int node = b * 256 + tid;
  if (node < NN) offsets[node] = gb + ex;
  if (b == BUCKETS - 1 && tid == 0) offsets[NN] = stot;
  __syncthreads();
  for (int j = tid; j < ecnt; j += 256) {
    uint_t e = ebuf[j];
    int p = atomicAdd(&scur[(e >> 16) & 255], 1);
    srclist[gb + p] = (ush_t)(e & 0xFFFFu);
  }
}

// ---------------------------------------------------------------------------
// XCD-sliced gather-mean (round-6 verified geometry: 4 chunks x 64 B
// requests, 16-deep uint4 issue) with ONLY the round-8-proven VALU cut:
//  - DPP quad_perm broadcast (1 VALU, no LDS pipe) replaces __shfl/ds_bpermute
//  - wave-uniform chunk base + 32-bit element offsets (no 64-bit addr chain)
// Loads/stores, issue depth, tail handling (s=0 fallback + j<m guard) and
// per-feature edge accumulation order are byte-identical to round 6
// -> bit-identical results.
// ---------------------------------------------------------------------------
#define ACC8(v)                                                  \
  a0 += bflo((v).x); a1 += bfhi((v).x); a2 += bflo((v).y);       \
  a3 += bfhi((v).y); a4 += bflo((v).z); a5 += bfhi((v).z);       \
  a6 += bflo((v).w); a7 += bfhi((v).w);

__global__ __launch_bounds__(256) void agg_k(const ush_t* __restrict__ xbc,
                                             const ush_t* __restrict__ srclist,
                                             const int* __restrict__ offsets,
                                             ush_t* __restrict__ meanb) {
  int bid = blockIdx.x;
  int chunk = bid & 3;
  int grp = bid >> 2;
  int tid = threadIdx.x;
  int node = grp * 64 + (tid >> 2);
  if (node >= NN) return;
  int l4 = tid & 3;
  const ush_t* cb = xbc + (size_t)chunk * NN * 32;  // wave-uniform chunk base
  int loff = l4 * 8;                                 // lane offset (elements)
  int beg = offsets[node];
  int end = offsets[node + 1];
  float a0 = 0.f, a1 = 0.f, a2 = 0.f, a3 = 0.f;
  float a4 = 0.f, a5 = 0.f, a6 = 0.f, a7 = 0.f;
  for (int c = beg; c < end; c += 16) {
    int m = end - c;
    int i0 = c + l4, i1 = c + 4 + l4, i2 = c + 8 + l4, i3 = c + 12 + l4;
    int s0 = (i0 < end) ? (int)srclist[i0] : 0;
    int s1 = (i1 < end) ? (int)srclist[i1] : 0;
    int s2 = (i2 < end) ? (int)srclist[i2] : 0;
    int s3 = (i3 < end) ? (int)srclist[i3] : 0;
    // quad_perm broadcast: lane j of each quad -> all 4 lanes (1 VALU op each)
    int t0 = __builtin_amdgcn_mov_dpp(s0, 0x00, 0xf, 0xf, false);
    int t1 = __builtin_amdgcn_mov_dpp(s0, 0x55, 0xf, 0xf, false);
    int t2 = __builtin_amdgcn_mov_dpp(s0, 0xAA, 0xf, 0xf, false);
    int t3 = __builtin_amdgcn_mov_dpp(s0, 0xFF, 0xf, 0xf, false);
    int t4 = __builtin_amdgcn_mov_dpp(s1, 0x00, 0xf, 0xf, false);
    int t5 = __builtin_amdgcn_mov_dpp(s1, 0x55, 0xf, 0xf, false);
    int t6 = __builtin_amdgcn_mov_dpp(s1, 0xAA, 0xf, 0xf, false);
    int t7 = __builtin_amdgcn_mov_dpp(s1, 0xFF, 0xf, 0xf, false);
    int t8 = __builtin_amdgcn_mov_dpp(s2, 0x00, 0xf, 0xf, false);
    int t9 = __builtin_amdgcn_mov_dpp(s2, 0x55, 0xf, 0xf, false);
    int tA = __builtin_amdgcn_mov_dpp(s2, 0xAA, 0xf, 0xf, false);
    int tB = __builtin_amdgcn_mov_dpp(s2, 0xFF, 0xf, 0xf, false);
    int tC = __builtin_amdgcn_mov_dpp(s3, 0x00, 0xf, 0xf, false);
    int tD = __builtin_amdgcn_mov_dpp(s3, 0x55, 0xf, 0xf, false);
    int tE = __builtin_amdgcn_mov_dpp(s3, 0xAA, 0xf, 0xf, false);
    int tF = __builtin_amdgcn_mov_dpp(s3, 0xFF, 0xf, 0xf, false);
    uint4 v[16];
    v[0]  = *reinterpret_cast<const uint4*>(cb + ((t0 << 5) + loff));
    v[1]  = *reinterpret_cast<const uint4*>(cb + ((t1 << 5) + loff));
    v[2]  = *reinterpret_cast<const uint4*>(cb + ((t2 << 5) + loff));
    v[3]  = *reinterpret_cast<const uint4*>(cb + ((t3 << 5) + loff));
    v[4]  = *reinterpret_cast<const uint4*>(cb + ((t4 << 5) + loff));
    v[5]  = *reinterpret_cast<const uint4*>(cb + ((t5 << 5) + loff));
    v[6]  = *reinterpret_cast<const uint4*>(cb + ((t6 << 5) + loff));
    v[7]  = *reinterpret_cast<const uint4*>(cb + ((t7 << 5) + loff));
    v[8]  = *reinterpret_cast<const uint4*>(cb + ((t8 << 5) + loff));
    v[9]  = *reinterpret_cast<const uint4*>(cb + ((t9 << 5) + loff));
    v[10] = *reinterpret_cast<const uint4*>(cb + ((tA << 5) + loff));
    v[11] = *reinterpret_cast<const uint4*>(cb + ((tB << 5) + loff));
    v[12] = *reinterpret_cast<const uint4*>(cb + ((tC << 5) + loff));
    v[13] = *reinterpret_cast<const uint4*>(cb + ((tD << 5) + loff));
    v[14] = *reinterpret_cast<const uint4*>(cb + ((tE << 5) + loff));
    v[15] = *reinterpret_cast<const uint4*>(cb + ((tF << 5) + loff));
#pragma unroll
    for (int j = 0; j < 16; ++j) {
      if (j < m) {  // uniform across the node's 4 lanes
        ACC8(v[j]);
      }
    }
  }
  float inv = 1.0f / fmaxf((float)(end - beg), 1.0f);
  uint4 o;
  o.x = pack2(a0 * inv, a1 * inv);
  o.y = pack2(a2 * inv, a3 * inv);
  o.z = pack2(a4 * inv, a5 * inv);
  o.w = pack2(a6 * inv, a7 * inv);
  *reinterpret_cast<uint4*>(meanb + (size_t)node * DD + chunk * 32 + loff) = o;
}

// ---------------------------------------------------------------------------
// Layer 1 + fused layer-2 contraction epilogue (round-3 verified structure).
// A0 from meanb [node][128]; A1 frags from 4-chunk xbc (16 rows x 64 B = 1 KB
// contiguous per wave-load); B (Wt1) in LDS.
// ---------------------------------------------------------------------------
__global__ __launch_bounds__(256, 2) void sage_l1(
    const ush_t* __restrict__ meanb, const ush_t* __restrict__ xbc,
    const ush_t* __restrict__ Wt1, const float* __restrict__ bl,
    const float* __restrict__ uv, float2* __restrict__ t12,
    float2* __restrict__ r12) {
  __shared__ ush_t sB[128 * BPAD];
  int tid = threadIdx.x;
  int lane = tid & 63;
  int wave = tid >> 6;
  int n15 = lane & 15, quad = lane >> 4;
  int nb = blockIdx.x * 64;
#pragma unroll
  for (int it = 0; it < 16; ++it) {
    int i = it * 256 + tid;
    int col = i >> 5, c = i & 31;
    *reinterpret_cast<short8*>(&sB[col * BPAD + c * 8]) =
        reinterpret_cast<const short8*>(Wt1)[i];
  }
  __syncthreads();
  int row = nb + wave * 16 + n15;
  int arow = (row < NN) ? row : (NN - 1);
  const ush_t* a0 = meanb + (size_t)arow * DD;
  f32x4 acc[8];
#pragma unroll
  for (int t = 0; t < 8; ++t) acc[t] = (f32x4){0.f, 0.f, 0.f, 0.f};
#pragma unroll
  for (int c = 0; c < 8; ++c) {
    short8 af;
    if (c < 4) {
      af = *reinterpret_cast<const short8*>(a0 + c * 32 + quad * 8);
    } else {
      af = *reinterpret_cast<const short8*>(
          xbc + ((size_t)(c - 4) * NN + arow) * 32 + quad * 8);
    }
    int kb = c * 32 + quad * 8;
#pragma unroll
    for (int t = 0; t < 8; ++t) {
      short8 bf = *reinterpret_cast<const short8*>(&sB[(t * 16 + n15) * BPAD + kb]);
      acc[t] = __builtin_amdgcn_mfma_f32_16x16x32_bf16(af, bf, acc[t], 0, 0, 0);
    }
  }
  float p1[4] = {0.f, 0.f, 0.f, 0.f};
  float p2[4] = {0.f, 0.f, 0.f, 0.f};
  float q1[4] = {0.f, 0.f, 0.f, 0.f};
  float q2[4] = {0.f, 0.f, 0.f, 0.f};
#pragma unroll
  for (int t = 0; t < 8; ++t) {
    int col = t * 16 + n15;
    float b = bl[col];
    float U1 = uv[col];
    float U2 = uv[128 + col];
    float V1 = uv[256 + col];
    float V2 = uv[384 + col];
#pragma unroll
    for (int reg = 0; reg < 4; ++reg) {
      float h = fmaxf(acc[t][reg] + b, 0.f);
      p1[reg] += h * U1;
      p2[reg] += h * U2;
      q1[reg] += h * V1;
      q2[reg] += h * V2;
    }
  }
#pragma unroll
  for (int reg = 0; reg < 4; ++reg) {
    float a1 = p1[reg], a2 = p2[reg], b1 = q1[reg], b2 = q2[reg];
    for (int off = 8; off > 0; off >>= 1) {
      a1 += __shfl_down(a1, off, 16);
      a2 += __shfl_down(a2, off, 16);
      b1 += __shfl_down(b1, off, 16);
      b2 += __shfl_down(b2, off, 16);
    }
    int r = nb + wave * 16 + quad * 4 + reg;
    if (n15 == 0 && r < NN) {
      t12[r] = make_float2(a1, a2);
      r12[r] = make_float2(b1, b2);
    }
  }
}

// ---------------------------------------------------------------------------
// Scalar second aggregation: s12[i] = mean_{j in N(i)} t12[j] + r12[i].
// ---------------------------------------------------------------------------
__global__ __launch_bounds__(256) void agg2s_k(const float2* __restrict__ t12,
                                               const ush_t* __restrict__ srclist,
                                               const int* __restrict__ offsets,
                                               const float2* __restrict__ r12,
                                               float2* __restrict__ s12) {
  int t = blockIdx.x * 256 + threadIdx.x;
  int node = t >> 4;
  int lane = t & 15;
  int beg = offsets[node];
  int end = offsets[node + 1];
  float sx = 0.f, sy = 0.f;
  for (int c = beg + lane; c < end; c += 16) {
    int s = srclist[c];
    float2 v = t12[s];
    sx += v.x;
    sy += v.y;
  }
  for (int off = 8; off > 0; off >>= 1) {
    sx += __shfl_down(sx, off, 16);
    sy += __shfl_down(sy, off, 16);
  }
  if (lane == 0) {
    float inv = 1.0f / fmaxf((float)(end - beg), 1.0f);
    float2 r = r12[node];
    s12[node] = make_float2(sx * inv + r.x, sy * inv + r.y);
  }
}

// ---------------------------------------------------------------------------
// Edge scores: y = sigmoid(s1[src] + s2[tgt] + cc), cc = b_l2.(We1+We2)+be.
// ---------------------------------------------------------------------------
__global__ __launch_bounds__(256) void edge_k(const uint_t* __restrict__ epk,
                                              const float2* __restrict__ s12,
                                              const float* __restrict__ cc,
                                              float* __restrict__ out) {
  int e = blockIdx.x * 256 + threadIdx.x;
  uint_t p = epk[e];
  float2 a = s12[p & 0xFFFFu];
  float2 b = s12[p >> 16];
  float v = a.x + b.y + cc[0];
  out[e] = 1.0f / (1.0f + __expf(-v));
}

extern "C" void kernel_launch(void* const* d_in, const int* in_sizes, int n_in,
                              void* d_out, int out_size, void* d_ws, size_t ws_size,
                              hipStream_t stream) {
  const float* x   = (const float*)d_in[0];
  const void*  ei  = d_in[1];
  const float* Wl1 = (const float*)d_in[2];
  const float* bl1 = (const float*)d_in[3];
  const float* Wr1 = (const float*)d_in[4];
  const float* Wl2 = (const float*)d_in[5];
  const float* bl2 = (const float*)d_in[6];
  const float* Wr2 = (const float*)d_in[7];
  const float* We  = (const float*)d_in[8];
  const float* be  = (const float*)d_in[9];
  float* out = (float*)d_out;

  // Workspace (every section 16B-aligned):
  // bcur[256] | offsets[50004] | epk[NE] | pbuf[BUCKETS*EMAX] |
  // srclist[NE ush] | xbc[NN*DD ush 4-chunk-major] | meanb[NN*DD ush] |
  // t12[NN f2] | r12[NN f2] | s12[NN f2] | Wt1[32768 ush] | uv[512 f] | cc[4 f]
  int* bcur       = (int*)d_ws;
  int* offsets    = bcur + 256;
  uint_t* epk     = (uint_t*)(offsets + 50004);
  uint_t* pbuf    = epk + NE;
  ush_t* srclist  = (ush_t*)(pbuf + (size_t)BUCKETS * EMAX);
  ush_t* xbc      = srclist + NE;
  ush_t* meanb    = xbc + (size_t)NN * DD;
  float2* t12     = (float2*)(meanb + (size_t)NN * DD);
  float2* r12     = t12 + NN;
  float2* s12     = r12 + NN;
  ush_t* Wt1      = (ush_t*)(s12 + NN);
  float* uv       = (float*)(Wt1 + 32768);
  float* cc       = uv + 512;

  hipMemsetAsync(bcur, 0, 256 * sizeof(int), stream);
  prep_part_k<<<PBLK + 3 + PACKB + WTB, 256, 0, stream>>>(
      ei, bcur, pbuf, epk, x, xbc, Wl1, Wr1, Wl2, Wr2, We, bl2, be, Wt1, uv, cc);
  csr_k<<<BUCKETS, 256, 0, stream>>>(pbuf, bcur, offsets, srclist);

  // 782 node-groups (64 nodes) x 4 XCD-pinned feature chunks
  agg_k<<<((NN + 63) / 64) * 4, 256, 0, stream>>>(xbc, srclist, offsets, meanb);

  sage_l1<<<(NN + 63) / 64, 256, 0, stream>>>(meanb, xbc, Wt1, bl1, uv, t12, r12);

  agg2s_k<<<(NN * 16) / 256, 256, 0, stream>>>(t12, srclist, offsets, r12, s12);

  edge_k<<<NE / 256, 256, 0, stream>>>(epk, s12, cc, out);
}